// Round 1
// baseline (322.661 us; speedup 1.0000x reference)
//
#include <hip/hip_runtime.h>
#include <hip/hip_bf16.h>

// Problem constants
#define BB 8
#define L1 64
#define LL 1024
#define DD 512   // DIM_IN == DIM_H == DIM_M == 512

// ---------------------------------------------------------------------------
// K1: qh[q,m] = sum_d query[q,d]*Wh[m,d] + bh[m]     (64x512, tiny)
// ---------------------------------------------------------------------------
__global__ __launch_bounds__(256) void qh_kernel(
    const float* __restrict__ query,  // [64,512]
    const float* __restrict__ Wh,     // [512,512]
    const float* __restrict__ bh,     // [512]
    float* __restrict__ qh) {         // [64,512]
  const int q = blockIdx.x;
  const int t = threadIdx.x;
  __shared__ float qs[DD];
  reinterpret_cast<float2*>(qs)[t] =
      reinterpret_cast<const float2*>(query + q * DD)[t];
  __syncthreads();
  #pragma unroll
  for (int mi = 0; mi < 2; ++mi) {
    const int m = t + mi * 256;
    const float* wr = Wh + m * DD;
    float acc = 0.f;
    for (int d = 0; d < DD; d += 4) {
      float4 wv = *reinterpret_cast<const float4*>(wr + d);
      acc += wv.x * qs[d] + wv.y * qs[d + 1] + wv.z * qs[d + 2] + wv.w * qs[d + 3];
    }
    qh[q * DD + m] = acc + bh[m];
  }
}

// ---------------------------------------------------------------------------
// K2: kx[row,m] = sum_d keys[row,d]*Wx[m,d]   row in [0,8192)
// Tiled f32 GEMM, 64x64 tile, BK=16, 256 threads, 4x4 per thread.
// ---------------------------------------------------------------------------
__global__ __launch_bounds__(256) void kx_kernel(
    const float* __restrict__ A,   // keys [8192,512]
    const float* __restrict__ W,   // Wx   [512,512]
    float* __restrict__ C) {       // kx   [8192,512]
  __shared__ float As[16][65];  // [k][row]
  __shared__ float Ws[16][65];  // [k][m]
  const int tid = threadIdx.x;
  const int tx = tid & 15, ty = tid >> 4;
  const int row0 = blockIdx.x * 64;
  const int col0 = blockIdx.y * 64;
  float acc[4][4] = {};
  const int r = tid >> 2;
  const int kq = (tid & 3) * 4;
  for (int k0 = 0; k0 < DD; k0 += 16) {
    float4 av = *reinterpret_cast<const float4*>(A + (row0 + r) * DD + k0 + kq);
    As[kq + 0][r] = av.x; As[kq + 1][r] = av.y;
    As[kq + 2][r] = av.z; As[kq + 3][r] = av.w;
    float4 wv = *reinterpret_cast<const float4*>(W + (col0 + r) * DD + k0 + kq);
    Ws[kq + 0][r] = wv.x; Ws[kq + 1][r] = wv.y;
    Ws[kq + 2][r] = wv.z; Ws[kq + 3][r] = wv.w;
    __syncthreads();
    #pragma unroll
    for (int kk = 0; kk < 16; ++kk) {
      float a[4], b[4];
      #pragma unroll
      for (int i = 0; i < 4; ++i) a[i] = As[kk][ty * 4 + i];
      #pragma unroll
      for (int j = 0; j < 4; ++j) b[j] = Ws[kk][tx * 4 + j];
      #pragma unroll
      for (int i = 0; i < 4; ++i)
        #pragma unroll
        for (int j = 0; j < 4; ++j) acc[i][j] += a[i] * b[j];
    }
    __syncthreads();
  }
  #pragma unroll
  for (int i = 0; i < 4; ++i) {
    float4 ov = make_float4(acc[i][0], acc[i][1], acc[i][2], acc[i][3]);
    *reinterpret_cast<float4*>(C + (row0 + ty * 4 + i) * DD + col0 + tx * 4) = ov;
  }
}

// ---------------------------------------------------------------------------
// K3: per (b,q) block: scores[l] = sum_m w[m]*relu(kx[b,l,m]+qh[q,m]),
//     softmax over l, write normalized e[b,q,l].
// 256 threads = 4 waves; wave-per-l with lane-over-m reduce.
// ---------------------------------------------------------------------------
__global__ __launch_bounds__(256) void score_kernel(
    const float* __restrict__ kx,   // [8,1024,512]
    const float* __restrict__ qh,   // [64,512]
    const float* __restrict__ w,    // [512]
    float* __restrict__ e) {        // [8,64,1024]
  const int bidx = blockIdx.x;
  const int b = bidx & 7;        // b -> XCD for L2 locality on kx[b]
  const int q = bidx >> 3;
  const int t = threadIdx.x;
  __shared__ float qs[DD];
  __shared__ float ws[DD];
  __shared__ float sc[LL];
  __shared__ float red_m[4];
  __shared__ float red_s[4];
  reinterpret_cast<float2*>(qs)[t] =
      reinterpret_cast<const float2*>(qh + q * DD)[t];
  reinterpret_cast<float2*>(ws)[t] = reinterpret_cast<const float2*>(w)[t];
  __syncthreads();
  const int lane = t & 63;
  const int wv = t >> 6;
  const float* kxb = kx + (size_t)b * LL * DD;
  for (int l = wv; l < LL; l += 4) {
    const float* kr = kxb + l * DD;
    float acc = 0.f;
    #pragma unroll
    for (int mi = 0; mi < DD / 64; ++mi) {
      const int m = lane + mi * 64;
      float g = kr[m] + qs[m];
      acc += ws[m] * fmaxf(g, 0.f);
    }
    #pragma unroll
    for (int off = 32; off > 0; off >>= 1) acc += __shfl_down(acc, off);
    if (lane == 0) sc[l] = acc;
  }
  __syncthreads();
  // block softmax over sc[0..1023]
  float m1 = -3.4e38f;
  for (int l = t; l < LL; l += 256) m1 = fmaxf(m1, sc[l]);
  #pragma unroll
  for (int off = 32; off > 0; off >>= 1) m1 = fmaxf(m1, __shfl_down(m1, off));
  if (lane == 0) red_m[wv] = m1;
  __syncthreads();
  const float m0 = fmaxf(fmaxf(red_m[0], red_m[1]), fmaxf(red_m[2], red_m[3]));
  float s1 = 0.f;
  for (int l = t; l < LL; l += 256) {
    float vv = __expf(sc[l] - m0);
    sc[l] = vv;
    s1 += vv;
  }
  #pragma unroll
  for (int off = 32; off > 0; off >>= 1) s1 += __shfl_down(s1, off);
  if (lane == 0) red_s[wv] = s1;
  __syncthreads();
  const float inv = 1.f / (red_s[0] + red_s[1] + red_s[2] + red_s[3]);
  float* er = e + ((size_t)b * L1 + q) * LL;
  for (int l = t; l < LL; l += 256) er[l] = sc[l] * inv;
}

// ---------------------------------------------------------------------------
// K4: out[b,q,d] = sum_l e[b,q,l]*values[b,l,d]
// Per b: [64,1024]@[1024,512]. Tiled 64x64, BK=16.
// ---------------------------------------------------------------------------
__global__ __launch_bounds__(256) void out_kernel(
    const float* __restrict__ e,   // [8,64,1024]
    const float* __restrict__ v,   // [8,1024,512]
    float* __restrict__ out) {     // [8,64,512]
  const int bidx = blockIdx.x;
  const int b = bidx & 7;
  const int col0 = (bidx >> 3) * 64;
  __shared__ float Es[16][65];  // [k][row]
  __shared__ float Vs[16][65];  // [k][col]
  const int tid = threadIdx.x;
  const int tx = tid & 15, ty = tid >> 4;
  float acc[4][4] = {};
  const float* E = e + (size_t)b * L1 * LL;
  const float* V = v + (size_t)b * LL * DD;
  const int r = tid >> 2;
  const int kq = (tid & 3) * 4;
  const int kk2 = tid >> 4;          // 0..15
  const int c4 = (tid & 15) * 4;     // 0..60
  for (int k0 = 0; k0 < LL; k0 += 16) {
    float4 ev = *reinterpret_cast<const float4*>(E + r * LL + k0 + kq);
    Es[kq + 0][r] = ev.x; Es[kq + 1][r] = ev.y;
    Es[kq + 2][r] = ev.z; Es[kq + 3][r] = ev.w;
    float4 vv = *reinterpret_cast<const float4*>(V + (k0 + kk2) * DD + col0 + c4);
    Vs[kk2][c4 + 0] = vv.x; Vs[kk2][c4 + 1] = vv.y;
    Vs[kk2][c4 + 2] = vv.z; Vs[kk2][c4 + 3] = vv.w;
    __syncthreads();
    #pragma unroll
    for (int kk = 0; kk < 16; ++kk) {
      float a[4], bb[4];
      #pragma unroll
      for (int i = 0; i < 4; ++i) a[i] = Es[kk][ty * 4 + i];
      #pragma unroll
      for (int j = 0; j < 4; ++j) bb[j] = Vs[kk][tx * 4 + j];
      #pragma unroll
      for (int i = 0; i < 4; ++i)
        #pragma unroll
        for (int j = 0; j < 4; ++j) acc[i][j] += a[i] * bb[j];
    }
    __syncthreads();
  }
  #pragma unroll
  for (int i = 0; i < 4; ++i) {
    float4 ov = make_float4(acc[i][0], acc[i][1], acc[i][2], acc[i][3]);
    *reinterpret_cast<float4*>(out + ((size_t)b * L1 + ty * 4 + i) * DD +
                               col0 + tx * 4) = ov;
  }
}

// ---------------------------------------------------------------------------
extern "C" void kernel_launch(void* const* d_in, const int* in_sizes, int n_in,
                              void* d_out, int out_size, void* d_ws, size_t ws_size,
                              hipStream_t stream) {
  const float* query  = (const float*)d_in[0];  // [64,512]
  const float* keys   = (const float*)d_in[1];  // [8,1024,512]
  const float* values = (const float*)d_in[2];  // [8,1024,512]
  const float* Wx     = (const float*)d_in[3];  // [512,512]
  const float* Wh     = (const float*)d_in[4];  // [512,512]
  const float* bh     = (const float*)d_in[5];  // [512]
  const float* w      = (const float*)d_in[6];  // [512]
  float* out = (float*)d_out;                   // [8,64,512]

  char* ws = (char*)d_ws;
  float* kx = (float*)ws;                                   // 16 MB
  float* qh = (float*)(ws + (size_t)BB * LL * DD * 4);      // 128 KB
  float* e  = (float*)(ws + (size_t)BB * LL * DD * 4 + (size_t)L1 * DD * 4);  // 2 MB

  qh_kernel<<<L1, 256, 0, stream>>>(query, Wh, bh, qh);
  kx_kernel<<<dim3((BB * LL) / 64, DD / 64), 256, 0, stream>>>(keys, Wx, kx);
  score_kernel<<<BB * L1, 256, 0, stream>>>(kx, qh, w, e);
  out_kernel<<<BB * (DD / 64), 256, 0, stream>>>(e, values, out);
}

// Round 2
// 173.039 us; speedup vs baseline: 1.8647x; 1.8647x over previous
//
#include <hip/hip_runtime.h>
#include <hip/hip_bf16.h>

// Problem constants
#define BB 8
#define L1 64
#define LL 1024
#define DD 512   // DIM_IN == DIM_H == DIM_M == 512

typedef float f32x4 __attribute__((ext_vector_type(4)));
typedef __bf16 bf16x8 __attribute__((ext_vector_type(8)));

static __device__ __forceinline__ unsigned short f2bf(float x) {
  unsigned int u = __builtin_bit_cast(unsigned int, x);
  unsigned int r = (u + 0x7fffu + ((u >> 16) & 1u)) >> 16;
  return (unsigned short)r;
}

// ---------------------------------------------------------------------------
// K1: qh[q,m] = sum_d query[q,d]*Wh[m,d] + bh[m]     (64x512, tiny)
// ---------------------------------------------------------------------------
__global__ __launch_bounds__(256) void qh_kernel(
    const float* __restrict__ query,  // [64,512]
    const float* __restrict__ Wh,     // [512,512]
    const float* __restrict__ bh,     // [512]
    float* __restrict__ qh) {         // [64,512]
  const int q = blockIdx.x;
  const int t = threadIdx.x;
  __shared__ float qs[DD];
  reinterpret_cast<float2*>(qs)[t] =
      reinterpret_cast<const float2*>(query + q * DD)[t];
  __syncthreads();
  #pragma unroll
  for (int mi = 0; mi < 2; ++mi) {
    const int m = t + mi * 256;
    const float* wr = Wh + m * DD;
    float acc = 0.f;
    for (int d = 0; d < DD; d += 4) {
      float4 wv = *reinterpret_cast<const float4*>(wr + d);
      acc += wv.x * qs[d] + wv.y * qs[d + 1] + wv.z * qs[d + 2] + wv.w * qs[d + 3];
    }
    qh[q * DD + m] = acc + bh[m];
  }
}

// ---------------------------------------------------------------------------
// K2: kx[row,m] = sum_d keys[row,d]*Wx[m,d]  via bf16 MFMA 16x16x32.
// 128x128 tile, BK=64, 4 waves (2x2), per-wave 4x4 fragments.
// f32->bf16 conversion fused into reg-staging; LDS XOR-swizzled (G4).
// ---------------------------------------------------------------------------
__global__ __launch_bounds__(256) void kx_mfma_kernel(
    const float* __restrict__ A,   // keys [8192,512]
    const float* __restrict__ W,   // Wx   [512,512]
    float* __restrict__ C) {       // kx   [8192,512]
  __shared__ char lds[32768] __attribute__((aligned(128)));
  // A tile: bytes [0,16384): [128 rows][64 k] bf16, row stride 128 B
  // B tile: bytes [16384,32768): same
  const int t = threadIdx.x;
  const int lane = t & 63;
  const int w = t >> 6;
  const int wr = w >> 1, wc = w & 1;
  const int fq = lane >> 4, fr = lane & 15;
  const int rowA0 = blockIdx.x * 128;
  const int m0 = blockIdx.y * 128;

  f32x4 acc[4][4] = {};

  for (int k0 = 0; k0 < DD; k0 += 64) {
    // ---- stage A and B (f32 -> bf16, swizzled ds_write) ----
    #pragma unroll
    for (int i = 0; i < 8; ++i) {
      int flat = t * 4 + i * 1024;      // elem in 128x64 tile
      int row = flat >> 6, col = flat & 63;
      float4 v = *reinterpret_cast<const float4*>(A + (size_t)(rowA0 + row) * DD + k0 + col);
      unsigned int lo = (unsigned int)f2bf(v.x) | ((unsigned int)f2bf(v.y) << 16);
      unsigned int hi = (unsigned int)f2bf(v.z) | ((unsigned int)f2bf(v.w) << 16);
      int byte = (row * 128 + col * 2) ^ ((row & 7) << 4);
      *reinterpret_cast<uint2*>(lds + byte) = make_uint2(lo, hi);
    }
    #pragma unroll
    for (int i = 0; i < 8; ++i) {
      int flat = t * 4 + i * 1024;
      int row = flat >> 6, col = flat & 63;
      float4 v = *reinterpret_cast<const float4*>(W + (size_t)(m0 + row) * DD + k0 + col);
      unsigned int lo = (unsigned int)f2bf(v.x) | ((unsigned int)f2bf(v.y) << 16);
      unsigned int hi = (unsigned int)f2bf(v.z) | ((unsigned int)f2bf(v.w) << 16);
      int byte = ((row * 128 + col * 2) ^ ((row & 7) << 4)) + 16384;
      *reinterpret_cast<uint2*>(lds + byte) = make_uint2(lo, hi);
    }
    __syncthreads();
    // ---- compute: 2 k-halves x 16 MFMA ----
    #pragma unroll
    for (int kh = 0; kh < 2; ++kh) {
      bf16x8 af[4], bf[4];
      #pragma unroll
      for (int mi = 0; mi < 4; ++mi) {
        int row = wr * 64 + mi * 16 + fr;
        int byte = (row * 128 + kh * 64 + fq * 16) ^ ((row & 7) << 4);
        af[mi] = *reinterpret_cast<const bf16x8*>(lds + byte);
      }
      #pragma unroll
      for (int ni = 0; ni < 4; ++ni) {
        int row = wc * 64 + ni * 16 + fr;
        int byte = ((row * 128 + kh * 64 + fq * 16) ^ ((row & 7) << 4)) + 16384;
        bf[ni] = *reinterpret_cast<const bf16x8*>(lds + byte);
      }
      #pragma unroll
      for (int mi = 0; mi < 4; ++mi)
        #pragma unroll
        for (int ni = 0; ni < 4; ++ni)
          acc[mi][ni] = __builtin_amdgcn_mfma_f32_16x16x32_bf16(
              af[mi], bf[ni], acc[mi][ni], 0, 0, 0);
    }
    __syncthreads();
  }
  // ---- epilogue: C[row][col], row=(lane>>4)*4+reg, col=lane&15 per frag ----
  #pragma unroll
  for (int mi = 0; mi < 4; ++mi) {
    #pragma unroll
    for (int ni = 0; ni < 4; ++ni) {
      int row = rowA0 + wr * 64 + mi * 16 + fq * 4;
      int col = m0 + wc * 64 + ni * 16 + fr;
      #pragma unroll
      for (int r = 0; r < 4; ++r)
        C[(size_t)(row + r) * DD + col] = acc[mi][ni][r];
    }
  }
}

// ---------------------------------------------------------------------------
// K3: scores[b,q,l] = sum_m w[m]*relu(kx[b,l,m]+qh[q,m])
// Block = (b, l-tile of 16) x all 64 q. Grid 512. kx read exactly once.
// Thread: 1 l x 4 q register tile over float4 m-chunks.
// ---------------------------------------------------------------------------
__global__ __launch_bounds__(256) void score2_kernel(
    const float* __restrict__ kx,   // [8,1024,512]
    const float* __restrict__ qh,   // [64,512]
    const float* __restrict__ w,    // [512]
    float* __restrict__ sc) {       // [8,64,1024]
  const int b = blockIdx.x & 7;
  const int l0 = (blockIdx.x >> 3) * 16;
  const int t = threadIdx.x;
  __shared__ float kxs[16][68];
  __shared__ float qhs[64][68];
  __shared__ float wsf[DD];
  reinterpret_cast<float2*>(wsf)[t] = reinterpret_cast<const float2*>(w)[t];
  const int q0 = (t & 15) * 4;
  const int lq = t >> 4;   // 0..15
  float acc[4] = {};
  for (int m0 = 0; m0 < DD; m0 += 64) {
    {  // stage kxs: 16x64 = 1024 elems = 1 float4/thread
      int flat = t * 4;
      int row = flat >> 6, col = flat & 63;
      *reinterpret_cast<float4*>(&kxs[row][col]) =
          *reinterpret_cast<const float4*>(kx + ((size_t)(b * LL + l0 + row)) * DD + m0 + col);
    }
    #pragma unroll
    for (int i = 0; i < 4; ++i) {  // stage qhs: 64x64 = 4096 elems
      int flat = t * 4 + i * 1024;
      int row = flat >> 6, col = flat & 63;
      *reinterpret_cast<float4*>(&qhs[row][col]) =
          *reinterpret_cast<const float4*>(qh + (size_t)row * DD + m0 + col);
    }
    __syncthreads();
    #pragma unroll 4
    for (int mm = 0; mm < 64; mm += 4) {
      float4 kv = *reinterpret_cast<const float4*>(&kxs[lq][mm]);
      float4 wv = *reinterpret_cast<const float4*>(&wsf[m0 + mm]);
      #pragma unroll
      for (int j = 0; j < 4; ++j) {
        float4 qv = *reinterpret_cast<const float4*>(&qhs[q0 + j][mm]);
        acc[j] += wv.x * fmaxf(kv.x + qv.x, 0.f) + wv.y * fmaxf(kv.y + qv.y, 0.f)
                + wv.z * fmaxf(kv.z + qv.z, 0.f) + wv.w * fmaxf(kv.w + qv.w, 0.f);
      }
    }
    __syncthreads();
  }
  #pragma unroll
  for (int j = 0; j < 4; ++j)
    sc[((size_t)b * L1 + q0 + j) * LL + l0 + lq] = acc[j];
}

// ---------------------------------------------------------------------------
// K3b: in-place softmax over l for each of the 512 (b,q) rows.
// ---------------------------------------------------------------------------
__global__ __launch_bounds__(256) void softmax_kernel(float* __restrict__ sc) {
  const int row = blockIdx.x;   // 0..511
  const int t = threadIdx.x;
  const int lane = t & 63, wv = t >> 6;
  float* s = sc + (size_t)row * LL;
  __shared__ float red_m[4];
  __shared__ float red_s[4];
  float4 v = reinterpret_cast<const float4*>(s)[t];
  float m = fmaxf(fmaxf(v.x, v.y), fmaxf(v.z, v.w));
  #pragma unroll
  for (int off = 32; off > 0; off >>= 1) m = fmaxf(m, __shfl_down(m, off));
  if (lane == 0) red_m[wv] = m;
  __syncthreads();
  const float m0 = fmaxf(fmaxf(red_m[0], red_m[1]), fmaxf(red_m[2], red_m[3]));
  float4 ev;
  ev.x = __expf(v.x - m0); ev.y = __expf(v.y - m0);
  ev.z = __expf(v.z - m0); ev.w = __expf(v.w - m0);
  float s1 = ev.x + ev.y + ev.z + ev.w;
  #pragma unroll
  for (int off = 32; off > 0; off >>= 1) s1 += __shfl_down(s1, off);
  if (lane == 0) red_s[wv] = s1;
  __syncthreads();
  const float inv = 1.f / (red_s[0] + red_s[1] + red_s[2] + red_s[3]);
  ev.x *= inv; ev.y *= inv; ev.z *= inv; ev.w *= inv;
  reinterpret_cast<float4*>(s)[t] = ev;
}

// ---------------------------------------------------------------------------
// K4: out[b,q,d] = sum_l e[b,q,l]*values[b,l,d]
// ---------------------------------------------------------------------------
__global__ __launch_bounds__(256) void out_kernel(
    const float* __restrict__ e,   // [8,64,1024]
    const float* __restrict__ v,   // [8,1024,512]
    float* __restrict__ out) {     // [8,64,512]
  const int bidx = blockIdx.x;
  const int b = bidx & 7;
  const int col0 = (bidx >> 3) * 64;
  __shared__ float Es[16][65];  // [k][row]
  __shared__ float Vs[16][65];  // [k][col]
  const int tid = threadIdx.x;
  const int tx = tid & 15, ty = tid >> 4;
  float acc[4][4] = {};
  const float* E = e + (size_t)b * L1 * LL;
  const float* V = v + (size_t)b * LL * DD;
  const int r = tid >> 2;
  const int kq = (tid & 3) * 4;
  const int kk2 = tid >> 4;          // 0..15
  const int c4 = (tid & 15) * 4;     // 0..60
  for (int k0 = 0; k0 < LL; k0 += 16) {
    float4 ev = *reinterpret_cast<const float4*>(E + r * LL + k0 + kq);
    Es[kq + 0][r] = ev.x; Es[kq + 1][r] = ev.y;
    Es[kq + 2][r] = ev.z; Es[kq + 3][r] = ev.w;
    float4 vv = *reinterpret_cast<const float4*>(V + (size_t)(k0 + kk2) * DD + col0 + c4);
    Vs[kk2][c4 + 0] = vv.x; Vs[kk2][c4 + 1] = vv.y;
    Vs[kk2][c4 + 2] = vv.z; Vs[kk2][c4 + 3] = vv.w;
    __syncthreads();
    #pragma unroll
    for (int kk = 0; kk < 16; ++kk) {
      float a[4], bb[4];
      #pragma unroll
      for (int i = 0; i < 4; ++i) a[i] = Es[kk][ty * 4 + i];
      #pragma unroll
      for (int j = 0; j < 4; ++j) bb[j] = Vs[kk][tx * 4 + j];
      #pragma unroll
      for (int i = 0; i < 4; ++i)
        #pragma unroll
        for (int j = 0; j < 4; ++j) acc[i][j] += a[i] * bb[j];
    }
    __syncthreads();
  }
  #pragma unroll
  for (int i = 0; i < 4; ++i) {
    float4 ov = make_float4(acc[i][0], acc[i][1], acc[i][2], acc[i][3]);
    *reinterpret_cast<float4*>(out + ((size_t)b * L1 + ty * 4 + i) * DD +
                               col0 + tx * 4) = ov;
  }
}

// ---------------------------------------------------------------------------
extern "C" void kernel_launch(void* const* d_in, const int* in_sizes, int n_in,
                              void* d_out, int out_size, void* d_ws, size_t ws_size,
                              hipStream_t stream) {
  const float* query  = (const float*)d_in[0];  // [64,512]
  const float* keys   = (const float*)d_in[1];  // [8,1024,512]
  const float* values = (const float*)d_in[2];  // [8,1024,512]
  const float* Wx     = (const float*)d_in[3];  // [512,512]
  const float* Wh     = (const float*)d_in[4];  // [512,512]
  const float* bh     = (const float*)d_in[5];  // [512]
  const float* w      = (const float*)d_in[6];  // [512]
  float* out = (float*)d_out;                   // [8,64,512]

  char* ws = (char*)d_ws;
  float* kx = (float*)ws;                                    // 16 MB
  float* qh = (float*)(ws + (size_t)BB * LL * DD * 4);       // 128 KB
  float* sc = (float*)(ws + (size_t)BB * LL * DD * 4 + (size_t)L1 * DD * 4);  // 2 MB (scores -> e in place)

  qh_kernel<<<L1, 256, 0, stream>>>(query, Wh, bh, qh);
  kx_mfma_kernel<<<dim3((BB * LL) / 128, DD / 128), 256, 0, stream>>>(keys, Wx, kx);
  score2_kernel<<<BB * (LL / 16), 256, 0, stream>>>(kx, qh, w, sc);
  softmax_kernel<<<BB * L1, 256, 0, stream>>>(sc);
  out_kernel<<<BB * (DD / 64), 256, 0, stream>>>(sc, values, out);
}

// Round 3
// 106.292 us; speedup vs baseline: 3.0356x; 1.6280x over previous
//
#include <hip/hip_runtime.h>
#include <hip/hip_bf16.h>

// Problem constants
#define BB 8
#define L1 64
#define LL 1024
#define DD 512   // DIM_IN == DIM_H == DIM_M == 512

typedef float f32x4 __attribute__((ext_vector_type(4)));
typedef __bf16 bf16x4 __attribute__((ext_vector_type(4)));
typedef __bf16 bf16x8 __attribute__((ext_vector_type(8)));

// ---------------------------------------------------------------------------
// K1: qh[q,m] = sum_d query[q,d]*Wh[m,d] + bh[m]     (64x512, tiny)
// ---------------------------------------------------------------------------
__global__ __launch_bounds__(256) void qh_kernel(
    const float* __restrict__ query,  // [64,512]
    const float* __restrict__ Wh,     // [512,512]
    const float* __restrict__ bh,     // [512]
    float* __restrict__ qh) {         // [64,512]
  const int q = blockIdx.x;
  const int t = threadIdx.x;
  __shared__ float qs[DD];
  reinterpret_cast<float2*>(qs)[t] =
      reinterpret_cast<const float2*>(query + q * DD)[t];
  __syncthreads();
  #pragma unroll
  for (int mi = 0; mi < 2; ++mi) {
    const int m = t + mi * 256;
    const float* wr = Wh + m * DD;
    float acc = 0.f;
    for (int d = 0; d < DD; d += 4) {
      float4 wv = *reinterpret_cast<const float4*>(wr + d);
      acc += wv.x * qs[d] + wv.y * qs[d + 1] + wv.z * qs[d + 2] + wv.w * qs[d + 3];
    }
    qh[q * DD + m] = acc + bh[m];
  }
}

// ---------------------------------------------------------------------------
// K2: kx[row,m] = sum_d keys[row,d]*Wx[m,d]  via bf16 MFMA 16x16x32.
// 128x128 tile, BK=64, 4 waves (2x2), per-wave 4x4 fragments.
// Native bf16 casts (v_cvt_pk_bf16_f32) in reg-staging; LDS XOR-swizzled.
// ---------------------------------------------------------------------------
__global__ __launch_bounds__(256) void kx_mfma_kernel(
    const float* __restrict__ A,   // keys [8192,512]
    const float* __restrict__ W,   // Wx   [512,512]
    float* __restrict__ C) {       // kx   [8192,512]
  __shared__ char lds[32768] __attribute__((aligned(128)));
  const int t = threadIdx.x;
  const int lane = t & 63;
  const int w = t >> 6;
  const int wr = w >> 1, wc = w & 1;
  const int fq = lane >> 4, fr = lane & 15;
  const int rowA0 = blockIdx.x * 128;
  const int m0 = blockIdx.y * 128;

  f32x4 acc[4][4] = {};

  for (int k0 = 0; k0 < DD; k0 += 64) {
    #pragma unroll
    for (int i = 0; i < 8; ++i) {
      int flat = t * 4 + i * 1024;      // elem in 128x64 tile
      int row = flat >> 6, col = flat & 63;
      float4 v = *reinterpret_cast<const float4*>(A + (size_t)(rowA0 + row) * DD + k0 + col);
      bf16x4 bv;
      bv[0] = (__bf16)v.x; bv[1] = (__bf16)v.y;
      bv[2] = (__bf16)v.z; bv[3] = (__bf16)v.w;
      int byte = (row * 128 + col * 2) ^ ((row & 7) << 4);
      *reinterpret_cast<bf16x4*>(lds + byte) = bv;
    }
    #pragma unroll
    for (int i = 0; i < 8; ++i) {
      int flat = t * 4 + i * 1024;
      int row = flat >> 6, col = flat & 63;
      float4 v = *reinterpret_cast<const float4*>(W + (size_t)(m0 + row) * DD + k0 + col);
      bf16x4 bv;
      bv[0] = (__bf16)v.x; bv[1] = (__bf16)v.y;
      bv[2] = (__bf16)v.z; bv[3] = (__bf16)v.w;
      int byte = ((row * 128 + col * 2) ^ ((row & 7) << 4)) + 16384;
      *reinterpret_cast<bf16x4*>(lds + byte) = bv;
    }
    __syncthreads();
    #pragma unroll
    for (int kh = 0; kh < 2; ++kh) {
      bf16x8 af[4], bfr[4];
      #pragma unroll
      for (int mi = 0; mi < 4; ++mi) {
        int row = wr * 64 + mi * 16 + fr;
        int byte = (row * 128 + kh * 64 + fq * 16) ^ ((row & 7) << 4);
        af[mi] = *reinterpret_cast<const bf16x8*>(lds + byte);
      }
      #pragma unroll
      for (int ni = 0; ni < 4; ++ni) {
        int row = wc * 64 + ni * 16 + fr;
        int byte = ((row * 128 + kh * 64 + fq * 16) ^ ((row & 7) << 4)) + 16384;
        bfr[ni] = *reinterpret_cast<const bf16x8*>(lds + byte);
      }
      #pragma unroll
      for (int mi = 0; mi < 4; ++mi)
        #pragma unroll
        for (int ni = 0; ni < 4; ++ni)
          acc[mi][ni] = __builtin_amdgcn_mfma_f32_16x16x32_bf16(
              af[mi], bfr[ni], acc[mi][ni], 0, 0, 0);
    }
    __syncthreads();
  }
  #pragma unroll
  for (int mi = 0; mi < 4; ++mi) {
    #pragma unroll
    for (int ni = 0; ni < 4; ++ni) {
      int row = rowA0 + wr * 64 + mi * 16 + fq * 4;
      int col = m0 + wc * 64 + ni * 16 + fr;
      #pragma unroll
      for (int r = 0; r < 4; ++r)
        C[(size_t)(row + r) * DD + col] = acc[mi][ni][r];
    }
  }
}

// ---------------------------------------------------------------------------
// K3: scores[b,q,l] = sum_m w[m]*relu(kx[b,l,m]+qh[q,m])
// Block = (b, l-tile of 16) x all 64 q. Grid 512. kx read exactly once.
// Thread t: l = t>>4, q in {t&15, +16, +32, +48}  (bank-clean qhs reads).
// ---------------------------------------------------------------------------
__global__ __launch_bounds__(256) void score2_kernel(
    const float* __restrict__ kx,   // [8,1024,512]
    const float* __restrict__ qh,   // [64,512]
    const float* __restrict__ w,    // [512]
    float* __restrict__ sc) {       // [8,64,1024]
  const int b = blockIdx.x & 7;
  const int l0 = (blockIdx.x >> 3) * 16;
  const int t = threadIdx.x;
  __shared__ float kxs[16][68];
  __shared__ float qhs[64][68];
  __shared__ float wsf[DD];
  reinterpret_cast<float2*>(wsf)[t] = reinterpret_cast<const float2*>(w)[t];
  const int qb = t & 15;
  const int lq = t >> 4;   // 0..15
  float acc[4] = {};
  for (int m0 = 0; m0 < DD; m0 += 64) {
    {  // stage kxs: 16x64 = 1024 elems = 1 float4/thread
      int flat = t * 4;
      int row = flat >> 6, col = flat & 63;
      *reinterpret_cast<float4*>(&kxs[row][col]) =
          *reinterpret_cast<const float4*>(kx + ((size_t)(b * LL + l0 + row)) * DD + m0 + col);
    }
    #pragma unroll
    for (int i = 0; i < 4; ++i) {  // stage qhs: 64x64 = 4096 elems
      int flat = t * 4 + i * 1024;
      int row = flat >> 6, col = flat & 63;
      *reinterpret_cast<float4*>(&qhs[row][col]) =
          *reinterpret_cast<const float4*>(qh + (size_t)row * DD + m0 + col);
    }
    __syncthreads();
    #pragma unroll 4
    for (int mm = 0; mm < 64; mm += 4) {
      float4 kv = *reinterpret_cast<const float4*>(&kxs[lq][mm]);
      float4 wv = *reinterpret_cast<const float4*>(&wsf[m0 + mm]);
      #pragma unroll
      for (int j = 0; j < 4; ++j) {
        float4 qv = *reinterpret_cast<const float4*>(&qhs[qb + 16 * j][mm]);
        acc[j] += wv.x * fmaxf(kv.x + qv.x, 0.f) + wv.y * fmaxf(kv.y + qv.y, 0.f)
                + wv.z * fmaxf(kv.z + qv.z, 0.f) + wv.w * fmaxf(kv.w + qv.w, 0.f);
      }
    }
    __syncthreads();
  }
  #pragma unroll
  for (int j = 0; j < 4; ++j)
    sc[((size_t)b * L1 + qb + 16 * j) * LL + l0 + lq] = acc[j];
}

// ---------------------------------------------------------------------------
// K3b: in-place softmax over l for each of the 512 (b,q) rows.
// ---------------------------------------------------------------------------
__global__ __launch_bounds__(256) void softmax_kernel(float* __restrict__ sc) {
  const int row = blockIdx.x;   // 0..511
  const int t = threadIdx.x;
  const int lane = t & 63, wv = t >> 6;
  float* s = sc + (size_t)row * LL;
  __shared__ float red_m[4];
  __shared__ float red_s[4];
  float4 v = reinterpret_cast<const float4*>(s)[t];
  float m = fmaxf(fmaxf(v.x, v.y), fmaxf(v.z, v.w));
  #pragma unroll
  for (int off = 32; off > 0; off >>= 1) m = fmaxf(m, __shfl_down(m, off));
  if (lane == 0) red_m[wv] = m;
  __syncthreads();
  const float m0 = fmaxf(fmaxf(red_m[0], red_m[1]), fmaxf(red_m[2], red_m[3]));
  float4 ev;
  ev.x = __expf(v.x - m0); ev.y = __expf(v.y - m0);
  ev.z = __expf(v.z - m0); ev.w = __expf(v.w - m0);
  float s1 = ev.x + ev.y + ev.z + ev.w;
  #pragma unroll
  for (int off = 32; off > 0; off >>= 1) s1 += __shfl_down(s1, off);
  if (lane == 0) red_s[wv] = s1;
  __syncthreads();
  const float inv = 1.f / (red_s[0] + red_s[1] + red_s[2] + red_s[3]);
  ev.x *= inv; ev.y *= inv; ev.z *= inv; ev.w *= inv;
  reinterpret_cast<float4*>(s)[t] = ev;
}

// ---------------------------------------------------------------------------
// K4: split-K partial GEMM: par[kc][b][q][d] = sum_{l in kc} e[b,q,l]*V[b,l,d]
// Grid 256 = 8 b x 4 dtile(128) x 8 kchunk(128). 256 threads, 4q x 8d each.
// ---------------------------------------------------------------------------
__global__ __launch_bounds__(256) void out3_kernel(
    const float* __restrict__ e,   // [8,64,1024]
    const float* __restrict__ v,   // [8,1024,512]
    float* __restrict__ par) {     // [8 kc][8 b][64 q][512 d]
  const int bid = blockIdx.x;
  const int b = bid & 7;
  const int dt = (bid >> 3) & 3;
  const int kc = bid >> 5;
  const int d0 = dt * 128;
  const int k0 = kc * 128;
  __shared__ float eT[64][65];    // [k][q]
  __shared__ float Vs[64][128];   // [k][d]
  const int t = threadIdx.x;
  const int tx = t & 15;          // d-group: d = d0 + tx*8
  const int ty = t >> 4;          // q-group: q = ty*4..+3
  float acc[4][8] = {};
  const float* E = e + (size_t)b * L1 * LL;
  const float* V = v + (size_t)b * LL * DD;
  #pragma unroll
  for (int s = 0; s < 2; ++s) {
    const int ks = k0 + s * 64;
    #pragma unroll
    for (int i = 0; i < 4; ++i) {   // e: 64q x 64k, transpose into eT
      int flat = t * 4 + i * 1024;
      int q = flat >> 6, kk = flat & 63;
      float4 ev = *reinterpret_cast<const float4*>(E + (size_t)q * LL + ks + kk);
      eT[kk + 0][q] = ev.x; eT[kk + 1][q] = ev.y;
      eT[kk + 2][q] = ev.z; eT[kk + 3][q] = ev.w;
    }
    #pragma unroll
    for (int i = 0; i < 8; ++i) {   // V: 64k x 128d
      int flat = t * 4 + i * 1024;
      int kk = flat >> 7, dd = flat & 127;
      *reinterpret_cast<float4*>(&Vs[kk][dd]) =
          *reinterpret_cast<const float4*>(V + (size_t)(ks + kk) * DD + d0 + dd);
    }
    __syncthreads();
    #pragma unroll 16
    for (int kk = 0; kk < 64; ++kk) {
      float4 ev = *reinterpret_cast<const float4*>(&eT[kk][ty * 4]);
      float4 v0 = *reinterpret_cast<const float4*>(&Vs[kk][tx * 8]);
      float4 v1 = *reinterpret_cast<const float4*>(&Vs[kk][tx * 8 + 4]);
      float ee[4] = {ev.x, ev.y, ev.z, ev.w};
      float vv[8] = {v0.x, v0.y, v0.z, v0.w, v1.x, v1.y, v1.z, v1.w};
      #pragma unroll
      for (int i = 0; i < 4; ++i)
        #pragma unroll
        for (int j = 0; j < 8; ++j) acc[i][j] += ee[i] * vv[j];
    }
    __syncthreads();
  }
  #pragma unroll
  for (int i = 0; i < 4; ++i) {
    float* p = par + (((size_t)(kc * 8 + b) * L1 + ty * 4 + i)) * DD + d0 + tx * 8;
    *reinterpret_cast<float4*>(p) = make_float4(acc[i][0], acc[i][1], acc[i][2], acc[i][3]);
    *reinterpret_cast<float4*>(p + 4) = make_float4(acc[i][4], acc[i][5], acc[i][6], acc[i][7]);
  }
}

// K4b: out[i] = sum_{c=0..7} par[c][i]   (fixed order, deterministic)
__global__ __launch_bounds__(256) void reduce_kernel(
    const float* __restrict__ par, float* __restrict__ out) {
  const int i = (blockIdx.x * 256 + threadIdx.x) * 4;   // float4 index
  f32x4 s = {};
  #pragma unroll
  for (int c = 0; c < 8; ++c) {
    f32x4 p = *reinterpret_cast<const f32x4*>(par + (size_t)c * (BB * L1 * DD) + i);
    s += p;
  }
  *reinterpret_cast<f32x4*>(out + i) = s;
}

// ---------------------------------------------------------------------------
extern "C" void kernel_launch(void* const* d_in, const int* in_sizes, int n_in,
                              void* d_out, int out_size, void* d_ws, size_t ws_size,
                              hipStream_t stream) {
  const float* query  = (const float*)d_in[0];  // [64,512]
  const float* keys   = (const float*)d_in[1];  // [8,1024,512]
  const float* values = (const float*)d_in[2];  // [8,1024,512]
  const float* Wx     = (const float*)d_in[3];  // [512,512]
  const float* Wh     = (const float*)d_in[4];  // [512,512]
  const float* bh     = (const float*)d_in[5];  // [512]
  const float* w      = (const float*)d_in[6];  // [512]
  float* out = (float*)d_out;                   // [8,64,512]

  char* ws = (char*)d_ws;
  float* kx = (float*)ws;                                        // 16 MB
  float* qh = (float*)(ws + 16777216);                           // 128 KB
  float* sc = (float*)(ws + 16777216 + 131072);                  // 2 MB
  float* par = (float*)(ws + 16777216 + 131072 + 2097152);       // 8 MB

  qh_kernel<<<L1, 256, 0, stream>>>(query, Wh, bh, qh);
  kx_mfma_kernel<<<dim3((BB * LL) / 128, DD / 128), 256, 0, stream>>>(keys, Wx, kx);
  score2_kernel<<<BB * (LL / 16), 256, 0, stream>>>(kx, qh, w, sc);
  softmax_kernel<<<BB * L1, 256, 0, stream>>>(sc);
  out3_kernel<<<256, 256, 0, stream>>>(sc, values, par);
  reduce_kernel<<<(BB * L1 * DD) / (256 * 4), 256, 0, stream>>>(par, out);
}

// Round 4
// 91.183 us; speedup vs baseline: 3.5386x; 1.1657x over previous
//
#include <hip/hip_runtime.h>
#include <hip/hip_bf16.h>

// Problem constants
#define BB 8
#define L1 64
#define LL 1024
#define DD 512   // DIM_IN == DIM_H == DIM_M == 512

typedef float f32x4 __attribute__((ext_vector_type(4)));
typedef _Float16 f16;
typedef _Float16 f16x2 __attribute__((ext_vector_type(2)));
typedef _Float16 f16x4 __attribute__((ext_vector_type(4)));
typedef _Float16 f16x8 __attribute__((ext_vector_type(8)));

union F16x8u { f16x8 v; f16x2 h[4]; };

// ---------------------------------------------------------------------------
// K1: qh[q,m] = sum_d query[q,d]*Wh[m,d] + bh[m]  -> f16   (64x512, tiny)
// ---------------------------------------------------------------------------
__global__ __launch_bounds__(256) void qh_kernel(
    const float* __restrict__ query,  // [64,512]
    const float* __restrict__ Wh,     // [512,512]
    const float* __restrict__ bh,     // [512]
    f16* __restrict__ qh) {           // [64,512] f16
  const int q = blockIdx.x;
  const int t = threadIdx.x;
  __shared__ float qs[DD];
  reinterpret_cast<float2*>(qs)[t] =
      reinterpret_cast<const float2*>(query + q * DD)[t];
  __syncthreads();
  #pragma unroll
  for (int mi = 0; mi < 2; ++mi) {
    const int m = t + mi * 256;
    const float* wr = Wh + m * DD;
    float acc = 0.f;
    for (int d = 0; d < DD; d += 4) {
      float4 wv = *reinterpret_cast<const float4*>(wr + d);
      acc += wv.x * qs[d] + wv.y * qs[d + 1] + wv.z * qs[d + 2] + wv.w * qs[d + 3];
    }
    qh[q * DD + m] = (f16)(acc + bh[m]);
  }
}

// ---------------------------------------------------------------------------
// K2: kx[row,m] = sum_d keys[row,d]*Wx[m,d]  via f16 MFMA 16x16x32 -> f16 out.
// 128x128 tile, BK=64, 4 waves (2x2), per-wave 4x4 fragments.
// LDS XOR-swizzled; f32->f16 conversion fused into reg-staging.
// ---------------------------------------------------------------------------
__global__ __launch_bounds__(256) void kx_mfma_kernel(
    const float* __restrict__ A,   // keys [8192,512] f32
    const float* __restrict__ W,   // Wx   [512,512]  f32
    f16* __restrict__ C) {         // kx   [8192,512] f16
  __shared__ char lds[32768] __attribute__((aligned(128)));
  const int t = threadIdx.x;
  const int lane = t & 63;
  const int w = t >> 6;
  const int wr = w >> 1, wc = w & 1;
  const int fq = lane >> 4, fr = lane & 15;
  const int rowA0 = blockIdx.x * 128;
  const int m0 = blockIdx.y * 128;

  f32x4 acc[4][4] = {};

  for (int k0 = 0; k0 < DD; k0 += 64) {
    #pragma unroll
    for (int i = 0; i < 8; ++i) {
      int flat = t * 4 + i * 1024;      // elem in 128x64 tile
      int row = flat >> 6, col = flat & 63;
      float4 v = *reinterpret_cast<const float4*>(A + (size_t)(rowA0 + row) * DD + k0 + col);
      f16x4 hv;
      hv[0] = (f16)v.x; hv[1] = (f16)v.y; hv[2] = (f16)v.z; hv[3] = (f16)v.w;
      int byte = (row * 128 + col * 2) ^ ((row & 7) << 4);
      *reinterpret_cast<f16x4*>(lds + byte) = hv;
    }
    #pragma unroll
    for (int i = 0; i < 8; ++i) {
      int flat = t * 4 + i * 1024;
      int row = flat >> 6, col = flat & 63;
      float4 v = *reinterpret_cast<const float4*>(W + (size_t)(m0 + row) * DD + k0 + col);
      f16x4 hv;
      hv[0] = (f16)v.x; hv[1] = (f16)v.y; hv[2] = (f16)v.z; hv[3] = (f16)v.w;
      int byte = ((row * 128 + col * 2) ^ ((row & 7) << 4)) + 16384;
      *reinterpret_cast<f16x4*>(lds + byte) = hv;
    }
    __syncthreads();
    #pragma unroll
    for (int kh = 0; kh < 2; ++kh) {
      f16x8 af[4], bfr[4];
      #pragma unroll
      for (int mi = 0; mi < 4; ++mi) {
        int row = wr * 64 + mi * 16 + fr;
        int byte = (row * 128 + kh * 64 + fq * 16) ^ ((row & 7) << 4);
        af[mi] = *reinterpret_cast<const f16x8*>(lds + byte);
      }
      #pragma unroll
      for (int ni = 0; ni < 4; ++ni) {
        int row = wc * 64 + ni * 16 + fr;
        int byte = ((row * 128 + kh * 64 + fq * 16) ^ ((row & 7) << 4)) + 16384;
        bfr[ni] = *reinterpret_cast<const f16x8*>(lds + byte);
      }
      #pragma unroll
      for (int mi = 0; mi < 4; ++mi)
        #pragma unroll
        for (int ni = 0; ni < 4; ++ni)
          acc[mi][ni] = __builtin_amdgcn_mfma_f32_16x16x32_f16(
              af[mi], bfr[ni], acc[mi][ni], 0, 0, 0);
    }
    __syncthreads();
  }
  #pragma unroll
  for (int mi = 0; mi < 4; ++mi) {
    #pragma unroll
    for (int ni = 0; ni < 4; ++ni) {
      int row = rowA0 + wr * 64 + mi * 16 + fq * 4;
      int col = m0 + wc * 64 + ni * 16 + fr;
      #pragma unroll
      for (int r = 0; r < 4; ++r)
        C[(size_t)(row + r) * DD + col] = (f16)acc[mi][ni][r];
    }
  }
}

// ---------------------------------------------------------------------------
// K3: scores[b,q,l] = sum_m w[m]*relu(kx[b,l,m]+qh[q,m])  — packed f16 math.
// Block = (b, l-tile of 16) x all 64 q. Grid 512 (2 blocks/CU).
// Thread t: l = l0 + (t>>4), q in {t&15, +16, +32, +48}.
// Per 8-m chunk x q: 4x v_pk_add_f16 + 4x v_pk_max_f16 + 4x v_dot2_f32_f16.
// ---------------------------------------------------------------------------
__global__ __launch_bounds__(256) void score3_kernel(
    const f16* __restrict__ kx,   // [8,1024,512] f16
    const f16* __restrict__ qh,   // [64,512] f16
    const float* __restrict__ w,  // [512] f32
    float* __restrict__ sc) {     // [8,64,1024] f32
  const int b = blockIdx.x & 7;
  const int l0 = (blockIdx.x >> 3) * 16;
  const int t = threadIdx.x;
  __shared__ __align__(16) f16 kxs[16][136];   // row stride 272B: conflict-free
  __shared__ __align__(16) f16 qhs[64][136];
  __shared__ __align__(16) f16 wsf[DD];
  if (t < 128) {
    float4 wv = *reinterpret_cast<const float4*>(w + t * 4);
    f16x4 hv; hv[0] = (f16)wv.x; hv[1] = (f16)wv.y; hv[2] = (f16)wv.z; hv[3] = (f16)wv.w;
    *reinterpret_cast<f16x4*>(&wsf[t * 4]) = hv;
  }
  const int qb = t & 15;
  const int lq = t >> 4;   // 0..15
  float acc[4] = {};
  for (int m0 = 0; m0 < DD; m0 += 128) {
    {  // stage kxs: 16 x 128 f16 = 1 uint4 per thread
      int flat = t * 8;
      int row = flat >> 7, col = flat & 127;
      *reinterpret_cast<uint4*>(&kxs[row][col]) =
          *reinterpret_cast<const uint4*>(kx + (size_t)(b * LL + l0 + row) * DD + m0 + col);
    }
    #pragma unroll
    for (int i = 0; i < 4; ++i) {  // stage qhs: 64 x 128 f16 = 4 uint4 per thread
      int flat = t * 8 + i * 2048;
      int row = flat >> 7, col = flat & 127;
      *reinterpret_cast<uint4*>(&qhs[row][col]) =
          *reinterpret_cast<const uint4*>(qh + (size_t)row * DD + m0 + col);
    }
    __syncthreads();
    #pragma unroll 4
    for (int mm = 0; mm < 128; mm += 8) {
      F16x8u kv, wv;
      kv.v = *reinterpret_cast<const f16x8*>(&kxs[lq][mm]);
      wv.v = *reinterpret_cast<const f16x8*>(&wsf[m0 + mm]);
      #pragma unroll
      for (int j = 0; j < 4; ++j) {
        F16x8u qv, g;
        qv.v = *reinterpret_cast<const f16x8*>(&qhs[qb + 16 * j][mm]);
        g.v = kv.v + qv.v;                       // v_pk_add_f16 x4
        f16x8 zz = {};
        g.v = __builtin_elementwise_max(g.v, zz);  // v_pk_max_f16 x4
        #pragma unroll
        for (int c = 0; c < 4; ++c)
          acc[j] = __builtin_amdgcn_fdot2(g.h[c], wv.h[c], acc[j], false);
      }
    }
    __syncthreads();
  }
  #pragma unroll
  for (int j = 0; j < 4; ++j)
    sc[((size_t)b * L1 + qb + 16 * j) * LL + l0 + lq] = acc[j];
}

// ---------------------------------------------------------------------------
// K3b: in-place softmax over l for each of the 512 (b,q) rows.
// ---------------------------------------------------------------------------
__global__ __launch_bounds__(256) void softmax_kernel(float* __restrict__ sc) {
  const int row = blockIdx.x;   // 0..511
  const int t = threadIdx.x;
  const int lane = t & 63, wv = t >> 6;
  float* s = sc + (size_t)row * LL;
  __shared__ float red_m[4];
  __shared__ float red_s[4];
  float4 v = reinterpret_cast<const float4*>(s)[t];
  float m = fmaxf(fmaxf(v.x, v.y), fmaxf(v.z, v.w));
  #pragma unroll
  for (int off = 32; off > 0; off >>= 1) m = fmaxf(m, __shfl_down(m, off));
  if (lane == 0) red_m[wv] = m;
  __syncthreads();
  const float m0 = fmaxf(fmaxf(red_m[0], red_m[1]), fmaxf(red_m[2], red_m[3]));
  float4 ev;
  ev.x = __expf(v.x - m0); ev.y = __expf(v.y - m0);
  ev.z = __expf(v.z - m0); ev.w = __expf(v.w - m0);
  float s1 = ev.x + ev.y + ev.z + ev.w;
  #pragma unroll
  for (int off = 32; off > 0; off >>= 1) s1 += __shfl_down(s1, off);
  if (lane == 0) red_s[wv] = s1;
  __syncthreads();
  const float inv = 1.f / (red_s[0] + red_s[1] + red_s[2] + red_s[3]);
  ev.x *= inv; ev.y *= inv; ev.z *= inv; ev.w *= inv;
  reinterpret_cast<float4*>(s)[t] = ev;
}

// ---------------------------------------------------------------------------
// K4: split-K partial GEMM: par[kc][b][q][d] = sum_{l in kc} e[b,q,l]*V[b,l,d]
// Grid 256 = 8 b x 4 dtile(128) x 8 kchunk(128). 256 threads, 4q x 8d each.
// ---------------------------------------------------------------------------
__global__ __launch_bounds__(256) void out3_kernel(
    const float* __restrict__ e,   // [8,64,1024]
    const float* __restrict__ v,   // [8,1024,512]
    float* __restrict__ par) {     // [8 kc][8 b][64 q][512 d]
  const int bid = blockIdx.x;
  const int b = bid & 7;
  const int dt = (bid >> 3) & 3;
  const int kc = bid >> 5;
  const int d0 = dt * 128;
  const int k0 = kc * 128;
  __shared__ float eT[64][65];    // [k][q]
  __shared__ float Vs[64][128];   // [k][d]
  const int t = threadIdx.x;
  const int tx = t & 15;          // d-group: d = d0 + tx*8
  const int ty = t >> 4;          // q-group: q = ty*4..+3
  float acc[4][8] = {};
  const float* E = e + (size_t)b * L1 * LL;
  const float* V = v + (size_t)b * LL * DD;
  #pragma unroll
  for (int s = 0; s < 2; ++s) {
    const int ks = k0 + s * 64;
    #pragma unroll
    for (int i = 0; i < 4; ++i) {   // e: 64q x 64k, transpose into eT
      int flat = t * 4 + i * 1024;
      int q = flat >> 6, kk = flat & 63;
      float4 ev = *reinterpret_cast<const float4*>(E + (size_t)q * LL + ks + kk);
      eT[kk + 0][q] = ev.x; eT[kk + 1][q] = ev.y;
      eT[kk + 2][q] = ev.z; eT[kk + 3][q] = ev.w;
    }
    #pragma unroll
    for (int i = 0; i < 8; ++i) {   // V: 64k x 128d
      int flat = t * 4 + i * 1024;
      int kk = flat >> 7, dd = flat & 127;
      *reinterpret_cast<float4*>(&Vs[kk][dd]) =
          *reinterpret_cast<const float4*>(V + (size_t)(ks + kk) * DD + d0 + dd);
    }
    __syncthreads();
    #pragma unroll 16
    for (int kk = 0; kk < 64; ++kk) {
      float4 ev = *reinterpret_cast<const float4*>(&eT[kk][ty * 4]);
      float4 v0 = *reinterpret_cast<const float4*>(&Vs[kk][tx * 8]);
      float4 v1 = *reinterpret_cast<const float4*>(&Vs[kk][tx * 8 + 4]);
      float ee[4] = {ev.x, ev.y, ev.z, ev.w};
      float vv[8] = {v0.x, v0.y, v0.z, v0.w, v1.x, v1.y, v1.z, v1.w};
      #pragma unroll
      for (int i = 0; i < 4; ++i)
        #pragma unroll
        for (int j = 0; j < 8; ++j) acc[i][j] += ee[i] * vv[j];
    }
    __syncthreads();
  }
  #pragma unroll
  for (int i = 0; i < 4; ++i) {
    float* p = par + (((size_t)(kc * 8 + b) * L1 + ty * 4 + i)) * DD + d0 + tx * 8;
    *reinterpret_cast<float4*>(p) = make_float4(acc[i][0], acc[i][1], acc[i][2], acc[i][3]);
    *reinterpret_cast<float4*>(p + 4) = make_float4(acc[i][4], acc[i][5], acc[i][6], acc[i][7]);
  }
}

// K4b: out[i] = sum_{c=0..7} par[c][i]   (fixed order, deterministic)
__global__ __launch_bounds__(256) void reduce_kernel(
    const float* __restrict__ par, float* __restrict__ out) {
  const int i = (blockIdx.x * 256 + threadIdx.x) * 4;   // float4 index
  f32x4 s = {};
  #pragma unroll
  for (int c = 0; c < 8; ++c) {
    f32x4 p = *reinterpret_cast<const f32x4*>(par + (size_t)c * (BB * L1 * DD) + i);
    s += p;
  }
  *reinterpret_cast<f32x4*>(out + i) = s;
}

// ---------------------------------------------------------------------------
extern "C" void kernel_launch(void* const* d_in, const int* in_sizes, int n_in,
                              void* d_out, int out_size, void* d_ws, size_t ws_size,
                              hipStream_t stream) {
  const float* query  = (const float*)d_in[0];  // [64,512]
  const float* keys   = (const float*)d_in[1];  // [8,1024,512]
  const float* values = (const float*)d_in[2];  // [8,1024,512]
  const float* Wx     = (const float*)d_in[3];  // [512,512]
  const float* Wh     = (const float*)d_in[4];  // [512,512]
  const float* bh     = (const float*)d_in[5];  // [512]
  const float* w      = (const float*)d_in[6];  // [512]
  float* out = (float*)d_out;                   // [8,64,512]

  char* ws = (char*)d_ws;
  f16*   kx  = (f16*)ws;                                   // 8 MB
  f16*   qh  = (f16*)(ws + 8388608);                       // 64 KB
  float* sc  = (float*)(ws + 8388608 + 65536);             // 2 MB
  float* par = (float*)(ws + 8388608 + 65536 + 2097152);   // 8 MB

  qh_kernel<<<L1, 256, 0, stream>>>(query, Wh, bh, qh);
  kx_mfma_kernel<<<dim3((BB * LL) / 128, DD / 128), 256, 0, stream>>>(keys, Wx, kx);
  score3_kernel<<<BB * (LL / 16), 256, 0, stream>>>(kx, qh, w, sc);
  softmax_kernel<<<BB * L1, 256, 0, stream>>>(sc);
  out3_kernel<<<256, 256, 0, stream>>>(sc, values, par);
  reduce_kernel<<<(BB * L1 * DD) / (256 * 4), 256, 0, stream>>>(par, out);
}

// Round 5
// 61.051 us; speedup vs baseline: 5.2851x; 1.4935x over previous
//
#include <hip/hip_runtime.h>
#include <hip/hip_bf16.h>

// Problem constants
#define BB 8
#define L1 64
#define LL 1024
#define DD 512   // DIM_IN == DIM_H == DIM_M == 512

typedef float f32x4 __attribute__((ext_vector_type(4)));
typedef _Float16 f16;
typedef _Float16 f16x2 __attribute__((ext_vector_type(2)));
typedef _Float16 f16x4 __attribute__((ext_vector_type(4)));
typedef _Float16 f16x8 __attribute__((ext_vector_type(8)));

union F16x8u { f16x8 v; f16x2 h[4]; };

// ---------------------------------------------------------------------------
// K1: fused kx + qh GEMM via f16 MFMA 16x16x32.
// blockIdx.x in [0,64): kx[row,m] = keys @ Wx^T   (128x128 tile)
// blockIdx.x == 64:     qh[q,m]  = query @ Wh^T + bh  (64 rows, duplicated)
// BK=64, 4 waves (2x2), per-wave 4x4 fragments. LDS XOR-swizzled.
// ---------------------------------------------------------------------------
__global__ __launch_bounds__(256) void kxqh_kernel(
    const float* __restrict__ keys,   // [8192,512] f32
    const float* __restrict__ query,  // [64,512]   f32
    const float* __restrict__ Wx,     // [512,512]  f32
    const float* __restrict__ Wh,     // [512,512]  f32
    const float* __restrict__ bh,     // [512]      f32
    f16* __restrict__ kx,             // [8192,512] f16
    f16* __restrict__ qh) {           // [64,512]   f16
  __shared__ char lds[32768] __attribute__((aligned(128)));
  const int t = threadIdx.x;
  const int lane = t & 63;
  const int w = t >> 6;
  const int wr = w >> 1, wc = w & 1;
  const int fq = lane >> 4, fr = lane & 15;
  const bool isQH = (blockIdx.x == 64);
  const int rowA0 = blockIdx.x * 128;
  const int m0 = blockIdx.y * 128;
  const float* Ap = isQH ? query : keys;
  const float* Wp = isQH ? Wh : Wx;

  f32x4 acc[4][4] = {};

  for (int k0 = 0; k0 < DD; k0 += 64) {
    #pragma unroll
    for (int i = 0; i < 8; ++i) {
      int flat = t * 4 + i * 1024;      // elem in 128x64 tile
      int row = flat >> 6, col = flat & 63;
      int arow = isQH ? (row & 63) : (rowA0 + row);
      float4 v = *reinterpret_cast<const float4*>(Ap + (size_t)arow * DD + k0 + col);
      f16x4 hv;
      hv[0] = (f16)v.x; hv[1] = (f16)v.y; hv[2] = (f16)v.z; hv[3] = (f16)v.w;
      int byte = (row * 128 + col * 2) ^ ((row & 7) << 4);
      *reinterpret_cast<f16x4*>(lds + byte) = hv;
    }
    #pragma unroll
    for (int i = 0; i < 8; ++i) {
      int flat = t * 4 + i * 1024;
      int row = flat >> 6, col = flat & 63;
      float4 v = *reinterpret_cast<const float4*>(Wp + (size_t)(m0 + row) * DD + k0 + col);
      f16x4 hv;
      hv[0] = (f16)v.x; hv[1] = (f16)v.y; hv[2] = (f16)v.z; hv[3] = (f16)v.w;
      int byte = ((row * 128 + col * 2) ^ ((row & 7) << 4)) + 16384;
      *reinterpret_cast<f16x4*>(lds + byte) = hv;
    }
    __syncthreads();
    #pragma unroll
    for (int kh = 0; kh < 2; ++kh) {
      f16x8 af[4], bfr[4];
      #pragma unroll
      for (int mi = 0; mi < 4; ++mi) {
        int row = wr * 64 + mi * 16 + fr;
        int byte = (row * 128 + kh * 64 + fq * 16) ^ ((row & 7) << 4);
        af[mi] = *reinterpret_cast<const f16x8*>(lds + byte);
      }
      #pragma unroll
      for (int ni = 0; ni < 4; ++ni) {
        int row = wc * 64 + ni * 16 + fr;
        int byte = ((row * 128 + kh * 64 + fq * 16) ^ ((row & 7) << 4)) + 16384;
        bfr[ni] = *reinterpret_cast<const f16x8*>(lds + byte);
      }
      #pragma unroll
      for (int mi = 0; mi < 4; ++mi)
        #pragma unroll
        for (int ni = 0; ni < 4; ++ni)
          acc[mi][ni] = __builtin_amdgcn_mfma_f32_16x16x32_f16(
              af[mi], bfr[ni], acc[mi][ni], 0, 0, 0);
    }
    __syncthreads();
  }
  if (isQH) {
    #pragma unroll
    for (int mi = 0; mi < 4; ++mi) {
      #pragma unroll
      for (int ni = 0; ni < 4; ++ni) {
        int row = wr * 64 + mi * 16 + fq * 4;
        int col = m0 + wc * 64 + ni * 16 + fr;
        if (row < 64) {
          float bias = bh[col];
          #pragma unroll
          for (int r = 0; r < 4; ++r)
            qh[(size_t)(row + r) * DD + col] = (f16)(acc[mi][ni][r] + bias);
        }
      }
    }
  } else {
    #pragma unroll
    for (int mi = 0; mi < 4; ++mi) {
      #pragma unroll
      for (int ni = 0; ni < 4; ++ni) {
        int row = rowA0 + wr * 64 + mi * 16 + fq * 4;
        int col = m0 + wc * 64 + ni * 16 + fr;
        #pragma unroll
        for (int r = 0; r < 4; ++r)
          kx[(size_t)(row + r) * DD + col] = (f16)acc[mi][ni][r];
      }
    }
  }
}

// ---------------------------------------------------------------------------
// K2: scores[b,q,l] = sum_m w[m]*relu(kx[b,l,m]+qh[q,m]) — packed f16 math.
// Block = (b, l-tile of 32) x all 64 q. Grid 256 (1 block/CU).
// Thread: 2 l x 4 q register tile (R=8): 7 b128 LDS reads per 16 results.
// ---------------------------------------------------------------------------
__global__ __launch_bounds__(256) void score4_kernel(
    const f16* __restrict__ kx,   // [8,1024,512] f16
    const f16* __restrict__ qh,   // [64,512] f16
    const float* __restrict__ w,  // [512] f32
    float* __restrict__ sc) {     // [8,64,1024] f32
  const int b = blockIdx.x & 7;
  const int l0 = (blockIdx.x >> 3) * 32;
  const int t = threadIdx.x;
  __shared__ __align__(16) f16 kxs[32][136];   // 272B row stride, all rows 16B-aligned
  __shared__ __align__(16) f16 qhs[64][136];
  __shared__ __align__(16) f16 wsf[DD];
  if (t < 128) {
    float4 wv = *reinterpret_cast<const float4*>(w + t * 4);
    f16x4 hv; hv[0] = (f16)wv.x; hv[1] = (f16)wv.y; hv[2] = (f16)wv.z; hv[3] = (f16)wv.w;
    *reinterpret_cast<f16x4*>(&wsf[t * 4]) = hv;
  }
  const int qb = t & 15;          // q in {qb, qb+16, qb+32, qb+48}
  const int lt = (t >> 4) * 2;    // l in {lt, lt+1}
  float acc[2][4] = {};
  for (int m0 = 0; m0 < DD; m0 += 128) {
    #pragma unroll
    for (int p = 0; p < 2; ++p) {  // kxs: 32 x 128 f16
      int flat = t * 8 + p * 2048;
      int row = flat >> 7, col = flat & 127;
      *reinterpret_cast<uint4*>(&kxs[row][col]) =
          *reinterpret_cast<const uint4*>(kx + (size_t)(b * LL + l0 + row) * DD + m0 + col);
    }
    #pragma unroll
    for (int p = 0; p < 4; ++p) {  // qhs: 64 x 128 f16
      int flat = t * 8 + p * 2048;
      int row = flat >> 7, col = flat & 127;
      *reinterpret_cast<uint4*>(&qhs[row][col]) =
          *reinterpret_cast<const uint4*>(qh + (size_t)row * DD + m0 + col);
    }
    __syncthreads();
    #pragma unroll 2
    for (int mm = 0; mm < 128; mm += 8) {
      F16x8u kv0, kv1, wv;
      kv0.v = *reinterpret_cast<const f16x8*>(&kxs[lt][mm]);
      kv1.v = *reinterpret_cast<const f16x8*>(&kxs[lt + 1][mm]);
      wv.v = *reinterpret_cast<const f16x8*>(&wsf[m0 + mm]);
      #pragma unroll
      for (int j = 0; j < 4; ++j) {
        F16x8u qv, g0, g1;
        qv.v = *reinterpret_cast<const f16x8*>(&qhs[qb + 16 * j][mm]);
        f16x8 zz = {};
        g0.v = __builtin_elementwise_max(kv0.v + qv.v, zz);
        g1.v = __builtin_elementwise_max(kv1.v + qv.v, zz);
        #pragma unroll
        for (int c = 0; c < 4; ++c) {
          acc[0][j] = __builtin_amdgcn_fdot2(g0.h[c], wv.h[c], acc[0][j], false);
          acc[1][j] = __builtin_amdgcn_fdot2(g1.h[c], wv.h[c], acc[1][j], false);
        }
      }
    }
    __syncthreads();
  }
  #pragma unroll
  for (int i = 0; i < 2; ++i)
    #pragma unroll
    for (int j = 0; j < 4; ++j)
      sc[((size_t)b * L1 + qb + 16 * j) * LL + l0 + lt + i] = acc[i][j];
}

// ---------------------------------------------------------------------------
// K3: softmax over l per (b,q) row; writes normalized e as f16.
// ---------------------------------------------------------------------------
__global__ __launch_bounds__(256) void softmax_kernel(
    const float* __restrict__ sc,   // [512,1024] f32
    f16* __restrict__ e) {          // [512,1024] f16
  const int row = blockIdx.x;   // 0..511
  const int t = threadIdx.x;
  const int lane = t & 63, wv = t >> 6;
  const float* s = sc + (size_t)row * LL;
  __shared__ float red_m[4];
  __shared__ float red_s[4];
  float4 v = reinterpret_cast<const float4*>(s)[t];
  float m = fmaxf(fmaxf(v.x, v.y), fmaxf(v.z, v.w));
  #pragma unroll
  for (int off = 32; off > 0; off >>= 1) m = fmaxf(m, __shfl_down(m, off));
  if (lane == 0) red_m[wv] = m;
  __syncthreads();
  const float m0 = fmaxf(fmaxf(red_m[0], red_m[1]), fmaxf(red_m[2], red_m[3]));
  float4 ev;
  ev.x = __expf(v.x - m0); ev.y = __expf(v.y - m0);
  ev.z = __expf(v.z - m0); ev.w = __expf(v.w - m0);
  float s1 = ev.x + ev.y + ev.z + ev.w;
  #pragma unroll
  for (int off = 32; off > 0; off >>= 1) s1 += __shfl_down(s1, off);
  if (lane == 0) red_s[wv] = s1;
  __syncthreads();
  const float inv = 1.f / (red_s[0] + red_s[1] + red_s[2] + red_s[3]);
  f16x4 hv;
  hv[0] = (f16)(ev.x * inv); hv[1] = (f16)(ev.y * inv);
  hv[2] = (f16)(ev.z * inv); hv[3] = (f16)(ev.w * inv);
  *reinterpret_cast<f16x4*>(e + (size_t)row * LL + t * 4) = hv;
}

// ---------------------------------------------------------------------------
// K4: split-K MFMA: par[kc][b][q][d] = sum_{l in kc} e[b,q,l]*V[b,l,d]
// Grid 256 = 8 b x 4 dtile(128) x 8 kchunk(128). 4 waves, each 64q x 32d.
// e staged [64][128] f16 swizzled; V staged transposed Vt[128 d][128 l] f16.
// ---------------------------------------------------------------------------
__global__ __launch_bounds__(256) void out4_kernel(
    const f16* __restrict__ e,    // [8,64,1024] f16
    const float* __restrict__ v,  // [8,1024,512] f32
    float* __restrict__ par) {    // [8 kc][8 b][64 q][512 d] f32
  __shared__ char lds[49152] __attribute__((aligned(128)));  // e@0 (16KB), Vt@16384 (32KB)
  const int bid = blockIdx.x;
  const int b = bid & 7;
  const int dt = (bid >> 3) & 3;
  const int kc = bid >> 5;
  const int d0 = dt * 128;
  const int k0 = kc * 128;
  const int t = threadIdx.x;
  const int lane = t & 63;
  const int w = t >> 6;
  const int fq = lane >> 4, fr = lane & 15;

  // stage e: [64 q][128 l] f16, XOR-swizzled rows
  #pragma unroll
  for (int p = 0; p < 4; ++p) {
    int flat = t * 8 + p * 2048;
    int row = flat >> 7, col = flat & 127;
    uint4 ev = *reinterpret_cast<const uint4*>(e + ((size_t)(b * L1 + row)) * LL + k0 + col);
    int byte = (row * 256 + col * 2) ^ ((row & 7) << 4);
    *reinterpret_cast<uint4*>(lds + byte) = ev;
  }
  // stage Vt: [128 d][128 l] f16 (transposed from V[k0+l][d0+d]), swizzled
  {
    const int dq = (t & 31) * 4;     // d base (4 cols)
    const int lq0 = (t >> 5) * 4;    // l base within 32-block
    #pragma unroll
    for (int p = 0; p < 4; ++p) {
      int lb = p * 32 + lq0;
      float vv[4][4];
      #pragma unroll
      for (int r = 0; r < 4; ++r) {
        float4 vr = *reinterpret_cast<const float4*>(
            v + (size_t)(b * LL + k0 + lb + r) * DD + d0 + dq);
        vv[r][0] = vr.x; vv[r][1] = vr.y; vv[r][2] = vr.z; vv[r][3] = vr.w;
      }
      #pragma unroll
      for (int j = 0; j < 4; ++j) {
        f16x4 cj;
        cj[0] = (f16)vv[0][j]; cj[1] = (f16)vv[1][j];
        cj[2] = (f16)vv[2][j]; cj[3] = (f16)vv[3][j];
        int d = dq + j;
        int byte = 16384 + ((d * 256 + lb * 2) ^ ((d & 7) << 4));
        *reinterpret_cast<f16x4*>(lds + byte) = cj;
      }
    }
  }
  __syncthreads();
  f32x4 acc[4][2] = {};
  const int nw = w * 32;   // wave d-offset
  #pragma unroll
  for (int ks = 0; ks < 4; ++ks) {
    f16x8 af[4], bf[2];
    #pragma unroll
    for (int mi = 0; mi < 4; ++mi) {
      int row = mi * 16 + fr;
      int byte = (row * 256 + ks * 64 + fq * 16) ^ ((row & 7) << 4);
      af[mi] = *reinterpret_cast<const f16x8*>(lds + byte);
    }
    #pragma unroll
    for (int ni = 0; ni < 2; ++ni) {
      int d = nw + ni * 16 + fr;
      int byte = 16384 + ((d * 256 + ks * 64 + fq * 16) ^ ((d & 7) << 4));
      bf[ni] = *reinterpret_cast<const f16x8*>(lds + byte);
    }
    #pragma unroll
    for (int mi = 0; mi < 4; ++mi)
      #pragma unroll
      for (int ni = 0; ni < 2; ++ni)
        acc[mi][ni] = __builtin_amdgcn_mfma_f32_16x16x32_f16(
            af[mi], bf[ni], acc[mi][ni], 0, 0, 0);
  }
  #pragma unroll
  for (int mi = 0; mi < 4; ++mi) {
    #pragma unroll
    for (int ni = 0; ni < 2; ++ni) {
      int q = mi * 16 + fq * 4;
      int d = d0 + nw + ni * 16 + fr;
      #pragma unroll
      for (int r = 0; r < 4; ++r)
        par[((size_t)(kc * 8 + b) * L1 + q + r) * DD + d] = acc[mi][ni][r];
    }
  }
}

// K4b: out[i] = sum_{c=0..7} par[c][i]   (fixed order, deterministic)
__global__ __launch_bounds__(256) void reduce_kernel(
    const float* __restrict__ par, float* __restrict__ out) {
  const int i = (blockIdx.x * 256 + threadIdx.x) * 4;   // float4 index
  f32x4 s = {};
  #pragma unroll
  for (int c = 0; c < 8; ++c) {
    f32x4 p = *reinterpret_cast<const f32x4*>(par + (size_t)c * (BB * L1 * DD) + i);
    s += p;
  }
  *reinterpret_cast<f32x4*>(out + i) = s;
}

// ---------------------------------------------------------------------------
extern "C" void kernel_launch(void* const* d_in, const int* in_sizes, int n_in,
                              void* d_out, int out_size, void* d_ws, size_t ws_size,
                              hipStream_t stream) {
  const float* query  = (const float*)d_in[0];  // [64,512]
  const float* keys   = (const float*)d_in[1];  // [8,1024,512]
  const float* values = (const float*)d_in[2];  // [8,1024,512]
  const float* Wx     = (const float*)d_in[3];  // [512,512]
  const float* Wh     = (const float*)d_in[4];  // [512,512]
  const float* bh     = (const float*)d_in[5];  // [512]
  const float* w      = (const float*)d_in[6];  // [512]
  float* out = (float*)d_out;                   // [8,64,512]

  char* ws = (char*)d_ws;
  f16*   kx   = (f16*)ws;                         // 8 MB
  f16*   qh   = (f16*)(ws + 8388608);             // 64 KB
  float* sc   = (float*)(ws + 8454144);           // 2 MB
  f16*   ef   = (f16*)(ws + 10551296);            // 1 MB
  float* par  = (float*)(ws + 11599872);          // 8 MB

  kxqh_kernel<<<dim3(65, DD / 128), 256, 0, stream>>>(keys, query, Wx, Wh, bh, kx, qh);
  score4_kernel<<<BB * (LL / 32), 256, 0, stream>>>(kx, qh, w, sc);
  softmax_kernel<<<BB * L1, 256, 0, stream>>>(sc, ef);
  out4_kernel<<<256, 256, 0, stream>>>(ef, values, par);
  reduce_kernel<<<(BB * L1 * DD) / (256 * 4), 256, 0, stream>>>(par, out);
}